// Round 3
// baseline (744.658 us; speedup 1.0000x reference)
//
#include <hip/hip_runtime.h>

typedef __bf16 bf16x8 __attribute__((ext_vector_type(8)));
typedef __bf16 bf16x4 __attribute__((ext_vector_type(4)));
typedef float  f32x4  __attribute__((ext_vector_type(4)));

#define MFMA(A,B,C) __builtin_amdgcn_mfma_f32_16x16x32_bf16((A),(B),(C),0,0,0)
// wave-local LDS RAW/WAR fence; sched_barrier stops MFMA hoisting past the wait (rule #18)
#define LDS_FENCE() do { asm volatile("s_waitcnt lgkmcnt(0)" ::: "memory"); \
                         __builtin_amdgcn_sched_barrier(0); } while (0)

// ---------------- geometry ----------------
// vid: (4, 256, 256, 256) fp32. windows: 4*32*32 = 4096, each 64 tokens x 256 ch.
// NH=8, hd=32, scale = 32^-0.5.
//
// LDS plan (43008 B -> 3 blocks/CU, was 80928 -> 2):
//   XO [33792 B]: x staging (af read per-kt inside gemms)  ->  attn-out
//   SC [ 9216 B]: per-wave 16x72 tile scratch for ALL C-layout->fragment
//                 transposes (q, k, v^T, P) done tile-by-tile
// rel-pos bias moved out of LDS: precomputed in global as C-layout f32x4
// fragments (block-invariant, 128 KB, L2-resident).

constexpr int XS_STRIDE = 264;   // x / attn-out rows (bf16); 528 B -> b128-friendly, 2-way banks
constexpr int SC_STRIDE = 72;    // tile stride; 144 B rows
constexpr int OFF_XO  = 0;       // 64*264*2 = 33792
constexpr int OFF_SC  = 33792;   // 4 waves * 16*72*2 = 9216
constexpr int LDS_BYTES = 43008; // 3 * 43008 = 129024 <= 163840

// ---------------- weight re-pack: B-fragment order ----------------
// wfrag[ct][kt][lane][j], ct 0..47 = concat(q,k,v) col-tiles, ct 48..63 = proj.
__global__ void prep_weights(const float* __restrict__ wq,
                             const float* __restrict__ wkv,
                             const float* __restrict__ projw,
                             __bf16* __restrict__ wfrag)
{
    const int lane = threadIdx.x & 63;
    const int kt   = threadIdx.x >> 6;       // 0..7
    const int ct   = blockIdx.x;             // 0..63
    const int nl   = lane & 15;
    const int kk0  = kt * 32 + ((lane >> 4) << 3);
    __bf16* dst = wfrag + (((size_t)ct * 8 + kt) * 64 + lane) * 8;
    bf16x8 o;
#pragma unroll
    for (int j = 0; j < 8; ++j) {
        const int kk = kk0 + j;
        float v;
        if (ct < 16)       v = wq  [kk * 256 +             ct        * 16 + nl];
        else if (ct < 32)  v = wkv [kk * 512 +             (ct - 16) * 16 + nl];
        else if (ct < 48)  v = wkv [kk * 512 + 256 +       (ct - 32) * 16 + nl];
        else               v = projw[kk * 256 +            (ct - 48) * 16 + nl];
        o[j] = (__bf16)v;
    }
    *(bf16x8*)dst = o;
}

// ---------------- rel-pos bias -> C-layout f32x4 fragments ----------------
// biasf[((h*4+mt)*4+nt)*64 + lane] = {bias[q(mt,lane,r)][k(nt,lane)] : r=0..3}
__global__ void prep_bias(const float* __restrict__ table, float* __restrict__ biasf)
{
    const int g    = blockIdx.x * 256 + threadIdx.x;   // 0..8191
    const int lane = g & 63;
    const int nt   = (g >> 6) & 3;
    const int mt   = (g >> 8) & 3;
    const int h    = g >> 10;
    const int colL = lane & 15;
    const int rowC = (lane >> 4) << 2;
    const int k     = nt * 16 + colL;
    const int kcode = (k >> 3) * 15 + (k & 7);
    f32x4 o;
#pragma unroll
    for (int r = 0; r < 4; ++r) {
        const int q     = mt * 16 + rowC + r;
        const int qcode = (q >> 3) * 15 + (q & 7) + 112;   // (dy+7)*15 + (dx+7)
        o[r] = table[(qcode - kcode) * 8 + h];
    }
    ((f32x4*)biasf)[g] = o;
}

// ---------------- fused per-window kernel ----------------
__global__ __launch_bounds__(256, 3)   // 3 blocks/CU target: cap regs ~168
void attn_fused(const float* __restrict__ vid,
                const float* __restrict__ mod,
                const float* __restrict__ bq,
                const float* __restrict__ bkv,
                const float* __restrict__ projb,
                const float* __restrict__ biasf,
                const __bf16* __restrict__ wfrag,
                float* __restrict__ out)
{
    extern __shared__ char smem[];
    __bf16* s_xo = (__bf16*)(smem + OFF_XO);    // x staging -> attn-out
    __bf16* s_tl = (__bf16*)(smem + OFF_SC) + (threadIdx.x >> 6) * (16 * SC_STRIDE);

    const int tid  = threadIdx.x;
    const int lane = tid & 63;
    const int wv   = tid >> 6;          // wave 0..3 (owns heads 2wv, 2wv+1)
    const int colL = lane & 15;
    const int quad = lane >> 4;
    const int kq   = quad << 3;         // A/B frag k-offset
    const int rowC = quad << 2;         // C/D row base

    const int b  = blockIdx.x;
    const int tt = b >> 10;
    const int wy = (b >> 5) & 31;
    const int wx = b & 31;
    const int base0 = tt * (1 << 24) + wy * 8 * 65536 + wx * 8 * 256;

    // ---- stage x + modulator (fp32 add, bf16 store) ----
#pragma unroll
    for (int i = 0; i < 16; ++i) {
        const int idx = tid + 256 * i;        // 0..4095
        const int m  = idx >> 6;
        const int c4 = (idx & 63) << 2;
        const int py = m >> 3, px = m & 7;
        const float4 xv = *(const float4*)(vid + base0 + py * 65536 + px * 256 + c4);
        const float4 mv = *(const float4*)(mod + m * 256 + c4);
        bf16x4 o;
        o[0] = (__bf16)(xv.x + mv.x);
        o[1] = (__bf16)(xv.y + mv.y);
        o[2] = (__bf16)(xv.z + mv.z);
        o[3] = (__bf16)(xv.w + mv.w);
        *(bf16x4*)&s_xo[m * XS_STRIDE + c4] = o;
    }
    __syncthreads();

    // ---- QKV gemms (kt-outer, af re-read from LDS -> low reg pressure) ----
    bf16x8 aq[2][4];        // q A-frags per head
    bf16x8 bk[2][4];        // k B-frags per head
    bf16x8 bv[2][2][2];     // v^T B-frags per head [n2][k2]

    auto gemm16 = [&](int part, const float* __restrict__ bias_p, f32x4 (&acc)[4][4]) {
        float bias[4];
#pragma unroll
        for (int ntl = 0; ntl < 4; ++ntl)
            bias[ntl] = bias_p[(wv * 4 + ntl) * 16 + colL];
#pragma unroll
        for (int ntl = 0; ntl < 4; ++ntl)
#pragma unroll
            for (int mt = 0; mt < 4; ++mt)
                acc[ntl][mt] = {bias[ntl], bias[ntl], bias[ntl], bias[ntl]};
        const int ct0 = part * 16 + wv * 4;
#pragma unroll
        for (int kt = 0; kt < 8; ++kt) {
            bf16x8 a[4];
#pragma unroll
            for (int mt = 0; mt < 4; ++mt)
                a[mt] = *(const bf16x8*)&s_xo[(mt * 16 + colL) * XS_STRIDE + kt * 32 + kq];
#pragma unroll
            for (int ntl = 0; ntl < 4; ++ntl) {
                const bf16x8 bf =
                    *((const bf16x8*)wfrag + ((size_t)(ct0 + ntl) * 8 + kt) * 64 + lane);
#pragma unroll
                for (int mt = 0; mt < 4; ++mt)
                    acc[ntl][mt] = MFMA(a[mt], bf, acc[ntl][mt]);
            }
        }
    };

    const float SCALE = 0.17677669529663687f;   // 32^-0.5

    // q: tile-transpose per mt through per-wave scratch -> aq frags (held)
    {
        f32x4 acc[4][4];
        gemm16(0, bq, acc);
#pragma unroll
        for (int mt = 0; mt < 4; ++mt) {
#pragma unroll
            for (int ntl = 0; ntl < 4; ++ntl)
#pragma unroll
                for (int r = 0; r < 4; ++r)
                    s_tl[(rowC + r) * SC_STRIDE + ntl * 16 + colL] =
                        (__bf16)(acc[ntl][mt][r] * SCALE);
            LDS_FENCE();
#pragma unroll
            for (int hh = 0; hh < 2; ++hh)
                aq[hh][mt] = *(const bf16x8*)&s_tl[colL * SC_STRIDE + hh * 32 + kq];
            LDS_FENCE();
        }
    }

    // k: same structure -> bk frags (held)
    {
        f32x4 acc[4][4];
        gemm16(1, bkv, acc);
#pragma unroll
        for (int nt = 0; nt < 4; ++nt) {
#pragma unroll
            for (int ntl = 0; ntl < 4; ++ntl)
#pragma unroll
                for (int r = 0; r < 4; ++r)
                    s_tl[(rowC + r) * SC_STRIDE + ntl * 16 + colL] = (__bf16)acc[ntl][nt][r];
            LDS_FENCE();
#pragma unroll
            for (int hh = 0; hh < 2; ++hh)
                bk[hh][nt] = *(const bf16x8*)&s_tl[colL * SC_STRIDE + hh * 32 + kq];
            LDS_FENCE();
        }
    }

    // v: per channel-tile ntl, v^T tile [16ch x 64tok] (packed b64 stores) -> bv frags
    {
        f32x4 acc[4][4];
        gemm16(2, bkv + 256, acc);
#pragma unroll
        for (int ntl = 0; ntl < 4; ++ntl) {
#pragma unroll
            for (int mt = 0; mt < 4; ++mt) {
                bf16x4 o;
                o[0] = (__bf16)acc[ntl][mt][0]; o[1] = (__bf16)acc[ntl][mt][1];
                o[2] = (__bf16)acc[ntl][mt][2]; o[3] = (__bf16)acc[ntl][mt][3];
                *(bf16x4*)&s_tl[colL * SC_STRIDE + mt * 16 + rowC] = o;
            }
            LDS_FENCE();
            const int hh = ntl >> 1, n2 = ntl & 1;
#pragma unroll
            for (int k2 = 0; k2 < 2; ++k2)
                bv[hh][n2][k2] = *(const bf16x8*)&s_tl[colL * SC_STRIDE + k2 * 32 + kq];
            LDS_FENCE();
        }
    }
    __syncthreads();   // all waves done reading x; XO becomes attn-out

    // ---- attention (wave-private heads), head-sequential to bound registers ----
    const f32x4* __restrict__ bfr = (const f32x4*)biasf;
#pragma unroll
    for (int hh = 0; hh < 2; ++hh) {
        const int h = 2 * wv + hh;
        f32x4 S[4][4];
#pragma unroll
        for (int mt = 0; mt < 4; ++mt)
#pragma unroll
            for (int nt = 0; nt < 4; ++nt)
                S[mt][nt] = MFMA(aq[hh][mt], bk[hh][nt],
                                 bfr[((h * 4 + mt) * 4 + nt) * 64 + lane]);

        // softmax over k (16 cols in-lane spread over colL lanes x 4 nt)
#pragma unroll
        for (int mt = 0; mt < 4; ++mt)
#pragma unroll
            for (int r = 0; r < 4; ++r) {
                float mx = S[mt][0][r];
#pragma unroll
                for (int nt = 1; nt < 4; ++nt) mx = fmaxf(mx, S[mt][nt][r]);
                mx = fmaxf(mx, __shfl_xor(mx, 1));
                mx = fmaxf(mx, __shfl_xor(mx, 2));
                mx = fmaxf(mx, __shfl_xor(mx, 4));
                mx = fmaxf(mx, __shfl_xor(mx, 8));
                float sum = 0.f;
#pragma unroll
                for (int nt = 0; nt < 4; ++nt) {
                    const float e = __expf(S[mt][nt][r] - mx);
                    S[mt][nt][r] = e;
                    sum += e;
                }
                sum += __shfl_xor(sum, 1);
                sum += __shfl_xor(sum, 2);
                sum += __shfl_xor(sum, 4);
                sum += __shfl_xor(sum, 8);
                const float inv = 1.0f / sum;
#pragma unroll
                for (int nt = 0; nt < 4; ++nt) S[mt][nt][r] *= inv;
            }

        // P tile-transpose + PV per mt; attn-out -> XO
#pragma unroll
        for (int mt = 0; mt < 4; ++mt) {
#pragma unroll
            for (int nt = 0; nt < 4; ++nt)
#pragma unroll
                for (int r = 0; r < 4; ++r)
                    s_tl[(rowC + r) * SC_STRIDE + nt * 16 + colL] = (__bf16)S[mt][nt][r];
            LDS_FENCE();
            const bf16x8 ap0 = *(const bf16x8*)&s_tl[colL * SC_STRIDE + kq];
            const bf16x8 ap1 = *(const bf16x8*)&s_tl[colL * SC_STRIDE + 32 + kq];
            LDS_FENCE();
#pragma unroll
            for (int n2 = 0; n2 < 2; ++n2) {
                f32x4 o = {0.f, 0.f, 0.f, 0.f};
                o = MFMA(ap0, bv[hh][n2][0], o);
                o = MFMA(ap1, bv[hh][n2][1], o);
#pragma unroll
                for (int r = 0; r < 4; ++r)
                    s_xo[(mt * 16 + rowC + r) * XS_STRIDE + h * 32 + n2 * 16 + colL] =
                        (__bf16)o[r];
            }
        }
    }
    __syncthreads();

    // ---- proj: [64x256] @ [256x256] + scatter back to vid layout ----
    {
        f32x4 acc[4][4];
        gemm16(3, projb, acc);
#pragma unroll
        for (int ntl = 0; ntl < 4; ++ntl) {
            const int n = (wv * 4 + ntl) * 16 + colL;
#pragma unroll
            for (int mt = 0; mt < 4; ++mt)
#pragma unroll
                for (int r = 0; r < 4; ++r) {
                    const int m = mt * 16 + rowC + r;
                    out[base0 + (m >> 3) * 65536 + (m & 7) * 256 + n] = acc[ntl][mt][r];
                }
        }
    }
}

extern "C" void kernel_launch(void* const* d_in, const int* in_sizes, int n_in,
                              void* d_out, int out_size, void* d_ws, size_t ws_size,
                              hipStream_t stream)
{
    const float* vid  = (const float*)d_in[0];
    const float* mod  = (const float*)d_in[1];
    const float* wq   = (const float*)d_in[2];
    const float* bq   = (const float*)d_in[3];
    const float* wkv  = (const float*)d_in[4];
    const float* bkv  = (const float*)d_in[5];
    const float* pw   = (const float*)d_in[6];
    const float* pb   = (const float*)d_in[7];
    const float* tab  = (const float*)d_in[8];
    __bf16* wfrag = (__bf16*)d_ws;                         // 512 KB
    float*  biasf = (float*)((char*)d_ws + 524288);        // 128 KB

    prep_weights<<<64, 512, 0, stream>>>(wq, wkv, pw, wfrag);
    prep_bias<<<32, 256, 0, stream>>>(tab, biasf);

    (void)hipFuncSetAttribute((const void*)attn_fused,
                              hipFuncAttributeMaxDynamicSharedMemorySize, LDS_BYTES);
    attn_fused<<<4096, 256, LDS_BYTES, stream>>>(vid, mod, bq, bkv, pb, biasf, wfrag,
                                                 (float*)d_out);
}